// Round 14
// baseline (77.286 us; speedup 1.0000x reference)
//
#include <hip/hip_runtime.h>

#define N_PP 100000
#define N_A  50000
#define N_AP 150000
#define NEDGE 500000
#define BSZ 8192
#define TILE 128
#define SCALE 1.44269504088896f   // log2(e)
#define QSI4 (1.0f / 7.0f)

#define GRID_W 1544               // 6176 pair jobs = exactly 4 per block
#define EPB 324                   // edges per block: 1544*324 = 500256 >= 500000
#define PP_JOBS 2080              // 64*65/2 upper-tri block pairs
#define AP_JOBS 4096
#define PJOBS (PP_JOBS + AP_JOBS) // 6176 = 4 * 1544

#define GRID_FB 2048              // fallback fused grid
#define EB_FB 977                 // fallback edge chunking (512 each)

typedef __attribute__((ext_vector_type(8)))  short bf16x8;
typedef __attribute__((ext_vector_type(16))) float f32x16;
typedef __attribute__((ext_vector_type(4)))  float f32x4;
typedef unsigned short u16;

#if __has_builtin(__builtin_amdgcn_sqrtf)
#define FAST_SQRT(x) __builtin_amdgcn_sqrtf(x)
#else
#define FAST_SQRT(x) sqrtf(x)
#endif
#if __has_builtin(__builtin_amdgcn_exp2f)
#define FAST_EXP2(x) __builtin_amdgcn_exp2f(x)
#else
#define FAST_EXP2(x) exp2f(x)
#endif

__device__ __forceinline__ u16 f2bf(float f) {
    unsigned u = __builtin_bit_cast(unsigned, f);
    u += 0x7FFFu + ((u >> 16) & 1u);
    return (u16)(u >> 16);
}
__device__ __forceinline__ float bf2f(u16 s) {
    unsigned u = ((unsigned)s) << 16;
    return __builtin_bit_cast(float, u);
}

__device__ __forceinline__ bf16x8 load_frag_f32(const float* __restrict__ src) {
    float4 v0 = *(const float4*)src;
    float4 v1 = *(const float4*)(src + 4);
    bf16x8 f;
    f[0] = (short)f2bf(v0.x); f[1] = (short)f2bf(v0.y);
    f[2] = (short)f2bf(v0.z); f[3] = (short)f2bf(v0.w);
    f[4] = (short)f2bf(v1.x); f[5] = (short)f2bf(v1.y);
    f[6] = (short)f2bf(v1.z); f[7] = (short)f2bf(v1.w);
    return f;
}

// ---- int4 row: 16 coords in 8 bytes (nibble c of word = coord c, signed) ----
__device__ __forceinline__ float dist_i4q(int2 ra, int2 rb) {
    int d2 = 0;
#pragma unroll
    for (int c = 0; c < 8; ++c) {
        int va = (ra.x << (28 - 4 * c)) >> 28;
        int vb = (rb.x << (28 - 4 * c)) >> 28;
        int d = va - vb; d2 += d * d;
        int wa = (ra.y << (28 - 4 * c)) >> 28;
        int wb = (rb.y << (28 - 4 * c)) >> 28;
        int e = wa - wb; d2 += e * e;
    }
    return FAST_SQRT((float)d2) * QSI4;
}

__device__ __forceinline__ unsigned packq4x8(const float* __restrict__ v) {
    unsigned r = 0;
#pragma unroll
    for (int c = 0; c < 8; ++c) {
        int q = (int)rintf(v[c] * 7.0f);
        r |= ((unsigned)(q & 0xF)) << (4 * c);
    }
    return r;
}

__device__ __forceinline__ float pdist16_f32(const float* __restrict__ xv,
                                             const float* __restrict__ yv) {
    float d2 = 1e-12f;
#pragma unroll
    for (int c = 0; c < 16; c += 4) {
        float4 xq = *(const float4*)(xv + c);
        float4 yq = *(const float4*)(yv + c);
        float dx = xq.x - yq.x; d2 = fmaf(dx, dx, d2);
        float dy = xq.y - yq.y; d2 = fmaf(dy, dy, d2);
        float dz = xq.z - yq.z; d2 = fmaf(dz, dz, d2);
        float dw = xq.w - yq.w; d2 = fmaf(dw, dw, d2);
    }
    return sqrtf(d2);
}

// ---------------- prep: int4 tables + bf16 weights + packed bf16 batch ----------------
__global__ __launch_bounds__(256) void prep_kernel(
        const float* __restrict__ p, const float* __restrict__ p_star,
        const float* __restrict__ a, const float* __restrict__ beta,
        const float* __restrict__ gamma,
        const int* __restrict__ psn, const int* __restrict__ pn,
        const int* __restrict__ an,
        int2* __restrict__ ps4, int2* __restrict__ p4, int2* __restrict__ a4,
        u16* __restrict__ gamma_h, u16* __restrict__ beta_h,
        u16* __restrict__ Xb, u16* __restrict__ Yp, u16* __restrict__ Ya,
        float* __restrict__ Xxx, float* __restrict__ Xg,
        float* __restrict__ Pyy, float* __restrict__ Pg,
        float* __restrict__ Ayy, float* __restrict__ Ag)
{
    const int NROWS = 250000;
    const int NBATCH = 3 * BSZ;
    const int NW = 2 * N_PP + N_AP;            // 350000 weight elements
    const int NITEMS = NROWS + NBATCH + NW;
    for (int i = blockIdx.x * 256 + threadIdx.x; i < NITEMS; i += gridDim.x * 256) {
        if (i < NROWS) {
            const float* src; int2* dst;
            if (i < 100000)      { src = p_star + (size_t)i * 16;       dst = ps4 + i; }
            else if (i < 200000) { src = p + (size_t)(i - 100000) * 16; dst = p4 + (i - 100000); }
            else                 { src = a + (size_t)(i - 200000) * 16; dst = a4 + (i - 200000); }
            float buf[16];
            *(float4*)(buf + 0)  = *(const float4*)(src + 0);
            *(float4*)(buf + 4)  = *(const float4*)(src + 4);
            *(float4*)(buf + 8)  = *(const float4*)(src + 8);
            *(float4*)(buf + 12) = *(const float4*)(src + 12);
            int2 q;
            q.x = (int)packq4x8(buf);
            q.y = (int)packq4x8(buf + 8);
            *dst = q;
        } else if (i < NROWS + NBATCH) {
            const int j = i - NROWS;
            const int which = j >> 13;
            const int r = j & (BSZ - 1);
            const float* src; float wsc; u16* drow; float* xxp; float* gp;
            if (which == 0) {
                int node = psn[r]; src = p_star + (size_t)node * 16;
                wsc = gamma[node] * SCALE; drow = Xb + (size_t)r * 16; xxp = Xxx; gp = Xg;
            } else if (which == 1) {
                int node = pn[r]; src = p + (size_t)node * 16;
                wsc = gamma[node + N_PP] * SCALE; drow = Yp + (size_t)r * 16; xxp = Pyy; gp = Pg;
            } else {
                int node = an[r]; src = a + (size_t)(node - N_PP) * 16;
                wsc = beta[node] * SCALE; drow = Ya + (size_t)r * 16; xxp = Ayy; gp = Ag;
            }
            bf16x8 lo = load_frag_f32(src);
            bf16x8 hi = load_frag_f32(src + 8);
            *(bf16x8*)drow = lo;
            *(bf16x8*)(drow + 8) = hi;
            float ss = 0.f;
#pragma unroll
            for (int c = 0; c < 8; ++c) {
                float q0 = bf2f((u16)lo[c]); ss = fmaf(q0, q0, ss);
                float q1 = bf2f((u16)hi[c]); ss = fmaf(q1, q1, ss);
            }
            xxp[r] = ss;
            gp[r] = wsc;
        } else {
            const int j = i - NROWS - NBATCH;
            if (j < 2 * N_PP) gamma_h[j] = f2bf(gamma[j]);
            else              beta_h[j - 2 * N_PP] = f2bf(beta[j - 2 * N_PP]);
        }
    }
}

// single-accumulator epilogue: one 32x32 quadrant (16 regs), stats loaded per q-group
template <bool DIAG>
__device__ __forceinline__ float epi_one(
        const f32x16& c,
        const float* __restrict__ xx, const float* __restrict__ gx,
        int rb, float yy, float gy, int cj)
{
    float s = 0.f;
#pragma unroll
    for (int q = 0; q < 4; ++q) {
        f32x4 xq = *(const f32x4*)&xx[rb + q * 8];
        f32x4 gq = *(const f32x4*)&gx[rb + q * 8];
#pragma unroll
        for (int j = 0; j < 4; ++j) {
            const int reg = q * 4 + j;
            float sq = fmaf(-2.f, c[reg], xq[j] + yy);
            float d  = FAST_SQRT(fmaxf(sq, 1e-12f));
            float v  = FAST_EXP2(fmaf(-SCALE, d, gq[j] + gy));
            if (DIAG) v = (cj > rb + q * 8 + j) ? v : 0.f;
            s += v;
        }
    }
    return s;
}

// two-acc epilogue for the fallback path
template <bool DIAG>
__device__ __forceinline__ float epi_rt(
        const f32x16& ca, const f32x16& cb,
        const float* __restrict__ xxg, const float* __restrict__ gxg,
        int rb, float yy0, float gy0, float yy1, float gy1,
        int cj0, int cj1)
{
    return epi_one<DIAG>(ca, xxg, gxg, rb, yy0, gy0, cj0)
         + epi_one<DIAG>(cb, xxg, gxg, rb, yy1, gy1, cj1);
}

__device__ __forceinline__ void decode_job(int j, int& bx, int& by, bool& pp) {
    pp = (j < PP_JOBS);
    if (pp) {
        int k = j;
        float disc = sqrtf((float)(129 * 129 - 8 * k));
        by = (int)((129.0f - disc) * 0.5f);
        while (64 * by - (by * (by - 1)) / 2 > k) --by;
        while (64 * (by + 1) - ((by + 1) * by) / 2 <= k) ++by;
        bx = by + (k - (64 * by - (by * (by - 1)) / 2));
    } else {
        int k = j - PP_JOBS;
        bx = k & 63; by = k >> 6;
    }
}

// ---------------- work kernel: 1544 blocks, perfectly uniform schedule -----------
// EVERY block: one 324-edge chunk + exactly 4 consecutive pair jobs [4b, 4b+4).
__global__ __launch_bounds__(256) void work_kernel(
        const int* __restrict__ edges_pp, const int* __restrict__ edges_ap,
        const int2* __restrict__ ps4, const int2* __restrict__ p4,
        const int2* __restrict__ a4,
        const u16* __restrict__ gamma_h, const u16* __restrict__ beta_h,
        const u16* __restrict__ Xb, const u16* __restrict__ Yp,
        const u16* __restrict__ Ya,
        const float* __restrict__ Xxx, const float* __restrict__ Xg,
        const float* __restrict__ Pyy, const float* __restrict__ Pg,
        const float* __restrict__ Ayy, const float* __restrict__ Ag,
        float* __restrict__ partials)
{
    const int b = blockIdx.x;
    const int t = threadIdx.x;
    const int l = t & 63, w = t >> 6;

    // ---------------- edge chunk: 324 edges, clamped-index masked loads ----------
    float s_ppl = 0.f, s_apl = 0.f;
    {
        const int base = b * EPB;
        const int i0r = base + t;
        const bool v0 = (t < EPB) && (i0r < NEDGE);
        const int i0 = v0 ? i0r : 0;
        const int i1r = base + 256 + t;
        const bool v1 = (256 + t < EPB) && (i1r < NEDGE);
        const int i1 = v1 ? i1r : 0;

        int e0a = __builtin_nontemporal_load(edges_pp + i0);
        int e1a = __builtin_nontemporal_load(edges_pp + NEDGE + i0);
        int f0a = __builtin_nontemporal_load(edges_ap + i0);
        int f1a = __builtin_nontemporal_load(edges_ap + NEDGE + i0);
        int e0b = __builtin_nontemporal_load(edges_pp + i1);
        int e1b = __builtin_nontemporal_load(edges_pp + NEDGE + i1);
        int f0b = __builtin_nontemporal_load(edges_ap + i1);
        int f1b = __builtin_nontemporal_load(edges_ap + NEDGE + i1);

        int2 rA0 = ps4[e0a];
        int2 rA1 = p4[e1a];
        int2 rB0 = ps4[f0a];
        int2 rB1 = a4[f1a - N_PP];
        int2 rC0 = ps4[e0b];
        int2 rC1 = p4[e1b];
        int2 rD0 = ps4[f0b];
        int2 rD1 = a4[f1b - N_PP];
        float wA = bf2f(gamma_h[e0a]) + bf2f(gamma_h[e1a + N_PP]);
        float wB = bf2f(beta_h[f0a])  + bf2f(beta_h[f1a]);
        float wC = bf2f(gamma_h[e0b]) + bf2f(gamma_h[e1b + N_PP]);
        float wD = bf2f(beta_h[f0b])  + bf2f(beta_h[f1b]);

        float t0pp = wA - dist_i4q(rA0, rA1);
        float t0ap = wB - dist_i4q(rB0, rB1);
        float t1pp = wC - dist_i4q(rC0, rC1);
        float t1ap = wD - dist_i4q(rD0, rD1);
        s_ppl = (v0 ? t0pp : 0.f) + (v1 ? t1pp : 0.f);
        s_apl = (v0 ? t0ap : 0.f) + (v1 ? t1ap : 0.f);
    }

    // ---------------- 4 consecutive pair jobs (L2-friendly row-panel reuse) ------
    const int wr = w >> 1, wc = w & 1;
    const int l31 = l & 31, h = l >> 5;
    const int cj0 = wc * 64 + l31, cj1 = cj0 + 32;
    const int rb0 = wr * 64 + 4 * h, rb1 = rb0 + 32;

    float s_ppn = 0.f, s_apn = 0.f;

#pragma unroll 1
    for (int j = 4 * b; j < 4 * b + 4; ++j) {
        int bx, by; bool pp;
        decode_job(j, bx, by, pp);
        const bool diag = pp && (bx == by);

        const u16* Ytab = pp ? Yp : Ya;
        const int ar0 = by * TILE + wr * 64 + l31;
        const int bc0 = bx * TILE + wc * 64 + l31;
        bf16x8 aF0 = *(const bf16x8*)(Xb   + (size_t)ar0 * 16 + h * 8);
        bf16x8 aF1 = *(const bf16x8*)(Xb   + (size_t)(ar0 + 32) * 16 + h * 8);
        bf16x8 bF0 = *(const bf16x8*)(Ytab + (size_t)bc0 * 16 + h * 8);
        bf16x8 bF1 = *(const bf16x8*)(Ytab + (size_t)(bc0 + 32) * 16 + h * 8);

        const float* yyP = (pp ? Pyy : Ayy) + bx * TILE;
        const float* gyP = (pp ? Pg  : Ag ) + bx * TILE;
        const float* xxg = Xxx + by * TILE;
        const float* gxg = Xg  + by * TILE;
        const float yy0 = yyP[cj0], gy0 = gyP[cj0];
        const float yy1 = yyP[cj1], gy1 = gyP[cj1];

        float sum = 0.f;
        {   // Q00: rows rb0, cols cj0
            f32x16 c;
#pragma unroll
            for (int i = 0; i < 16; ++i) c[i] = 0.f;
            c = __builtin_amdgcn_mfma_f32_32x32x16_bf16(aF0, bF0, c, 0, 0, 0);
            sum += diag ? epi_one<true >(c, xxg, gxg, rb0, yy0, gy0, cj0)
                        : epi_one<false>(c, xxg, gxg, rb0, yy0, gy0, cj0);
        }
        {   // Q01: rows rb0, cols cj1
            f32x16 c;
#pragma unroll
            for (int i = 0; i < 16; ++i) c[i] = 0.f;
            c = __builtin_amdgcn_mfma_f32_32x32x16_bf16(aF0, bF1, c, 0, 0, 0);
            sum += diag ? epi_one<true >(c, xxg, gxg, rb0, yy1, gy1, cj1)
                        : epi_one<false>(c, xxg, gxg, rb0, yy1, gy1, cj1);
        }
        {   // Q10: rows rb1, cols cj0
            f32x16 c;
#pragma unroll
            for (int i = 0; i < 16; ++i) c[i] = 0.f;
            c = __builtin_amdgcn_mfma_f32_32x32x16_bf16(aF1, bF0, c, 0, 0, 0);
            sum += diag ? epi_one<true >(c, xxg, gxg, rb1, yy0, gy0, cj0)
                        : epi_one<false>(c, xxg, gxg, rb1, yy0, gy0, cj0);
        }
        {   // Q11: rows rb1, cols cj1
            f32x16 c;
#pragma unroll
            for (int i = 0; i < 16; ++i) c[i] = 0.f;
            c = __builtin_amdgcn_mfma_f32_32x32x16_bf16(aF1, bF1, c, 0, 0, 0);
            sum += diag ? epi_one<true >(c, xxg, gxg, rb1, yy1, gy1, cj1)
                        : epi_one<false>(c, xxg, gxg, rb1, yy1, gy1, cj1);
        }
        if (pp) s_ppn += sum; else s_apn += sum;
    }

    // ---- one block reduction: 4 categories -> partials[b][4] ----
    __shared__ float red4[4][4];
    float v4[4] = {s_ppl, s_ppn, s_apl, s_apn};
#pragma unroll
    for (int c = 0; c < 4; ++c) {
        float r = v4[c];
#pragma unroll
        for (int o = 32; o > 0; o >>= 1) r += __shfl_down(r, o, 64);
        if (l == 0) red4[w][c] = r;
    }
    __syncthreads();
    if (t < 4)
        partials[(size_t)b * 4 + t] =
            red4[0][t] + red4[1][t] + red4[2][t] + red4[3][t];
}

// ---------------- finalize: fp64 reduce of per-block partials[n][4] ----------------
__global__ __launch_bounds__(256) void finalize_n(
        const float* __restrict__ partials, int n, float* __restrict__ out)
{
    __shared__ double acc4[4];
    const int t = threadIdx.x;
    const int c = t >> 6, l = t & 63;
    double s = 0.0;
    for (int i = l; i < n; i += 64) s += (double)partials[(size_t)i * 4 + c];
#pragma unroll
    for (int o = 32; o > 0; o >>= 1) s += __shfl_down(s, o, 64);
    if (l == 0) acc4[c] = s;
    __syncthreads();
    if (t == 0) {
        double nll_pp = -(acc4[0] - acc4[1]);
        double nll_ap = -(acc4[2] - acc4[3]);
        out[0] = (float)(0.5 * nll_pp / (double)BSZ + 0.5 * nll_ap / (double)BSZ);
    }
}

// ---------------- fallback fused kernel (no workspace tables) ----------------
__global__ __launch_bounds__(256) void fused_fb(
        const float* __restrict__ p, const float* __restrict__ p_star,
        const float* __restrict__ a, const float* __restrict__ beta,
        const float* __restrict__ gamma,
        const int* __restrict__ edges_pp, const int* __restrict__ edges_ap,
        const int* __restrict__ psn, const int* __restrict__ pn,
        const int* __restrict__ an, float* __restrict__ partials)
{
    const int t = threadIdx.x;
    const int l = t & 63, w = t >> 6;
    const int wr = w >> 1, wc = w & 1;
    const int l31 = l & 31, h = l >> 5;

    __shared__ float sxx[TILE], sgx[TILE], syy[TILE], sgy[TILE];
    __shared__ float red4[4][4];

    float s_ppl = 0.f, s_ppn = 0.f, s_apl = 0.f, s_apn = 0.f;
    const int NJ = EB_FB + PP_JOBS + AP_JOBS;

    for (int j = blockIdx.x; j < NJ; j += gridDim.x) {
        if (j < EB_FB) {
            const int base = j * 512;
#pragma unroll
            for (int k = 0; k < 2; ++k) {
                int i = base + k * 256 + t;
                if (i < NEDGE) {
                    int e0 = edges_pp[i], e1 = edges_pp[NEDGE + i];
                    int f0 = edges_ap[i], f1 = edges_ap[NEDGE + i];
                    s_ppl += gamma[e0] + gamma[e1 + N_PP]
                           - pdist16_f32(p_star + (size_t)e0 * 16, p + (size_t)e1 * 16);
                    s_apl += beta[f0] + beta[f1]
                           - pdist16_f32(p_star + (size_t)f0 * 16, a + (size_t)(f1 - N_PP) * 16);
                }
            }
        } else {
            const bool pp = (j < EB_FB + PP_JOBS);
            int bx, by;
            if (pp) {
                int k = j - EB_FB;
                float disc = sqrtf((float)(129 * 129 - 8 * k));
                by = (int)((129.0f - disc) * 0.5f);
                while (64 * by - (by * (by - 1)) / 2 > k) --by;
                while (64 * (by + 1) - ((by + 1) * by) / 2 <= k) ++by;
                bx = by + (k - (64 * by - (by * (by - 1)) / 2));
            } else {
                int k = j - EB_FB - PP_JOBS;
                bx = k & 63; by = k >> 6;
            }
            const bool diag = pp && (bx == by);
            const float* Y  = pp ? p : a;
            const float* wv = pp ? gamma : beta;
            const int* yn   = pp ? pn : an;
            const int wyo   = pp ? N_PP : 0;
            const int yvo   = pp ? 0 : -N_PP;
            const int ar0 = by * TILE + wr * 64 + l31;
            const int an0 = psn[ar0], an1 = psn[ar0 + 32];
            bf16x8 aF0 = load_frag_f32(p_star + (size_t)an0 * 16 + h * 8);
            bf16x8 aF1 = load_frag_f32(p_star + (size_t)an1 * 16 + h * 8);
            const int bc0g = bx * TILE + wc * 64 + l31;
            const int bn0 = yn[bc0g], bn1 = yn[bc0g + 32];
            bf16x8 bF0 = load_frag_f32(Y + (size_t)(bn0 + yvo) * 16 + h * 8);
            bf16x8 bF1 = load_frag_f32(Y + (size_t)(bn1 + yvo) * 16 + h * 8);
            {
                const bool isx = (t < 128);
                const int  r   = isx ? t : t - 128;
                const int  node = isx ? psn[by * TILE + r] : yn[bx * TILE + r];
                const float* src = isx ? (p_star + (size_t)node * 16)
                                       : (Y + (size_t)(node + yvo) * 16);
                float ss = 0.f;
#pragma unroll
                for (int c = 0; c < 16; c += 4) {
                    float4 v = *(const float4*)(src + c);
                    float q0 = bf2f(f2bf(v.x)), q1 = bf2f(f2bf(v.y));
                    float q2 = bf2f(f2bf(v.z)), q3 = bf2f(f2bf(v.w));
                    ss = fmaf(q0, q0, ss); ss = fmaf(q1, q1, ss);
                    ss = fmaf(q2, q2, ss); ss = fmaf(q3, q3, ss);
                }
                if (isx) { sxx[r] = ss; sgx[r] = wv[node] * SCALE; }
                else     { syy[r] = ss; sgy[r] = wv[node + wyo] * SCALE; }
            }
            __syncthreads();
            const int cj0 = wc * 64 + l31, cj1 = cj0 + 32;
            const float yy0 = syy[cj0], gy0 = sgy[cj0];
            const float yy1 = syy[cj1], gy1 = sgy[cj1];
            const int rb0 = wr * 64 + 4 * h, rb1 = rb0 + 32;

            f32x16 c00, c01, c10, c11;
#pragma unroll
            for (int i = 0; i < 16; ++i) { c00[i] = 0.f; c01[i] = 0.f; c10[i] = 0.f; c11[i] = 0.f; }
            c00 = __builtin_amdgcn_mfma_f32_32x32x16_bf16(aF0, bF0, c00, 0, 0, 0);
            c01 = __builtin_amdgcn_mfma_f32_32x32x16_bf16(aF0, bF1, c01, 0, 0, 0);
            c10 = __builtin_amdgcn_mfma_f32_32x32x16_bf16(aF1, bF0, c10, 0, 0, 0);
            c11 = __builtin_amdgcn_mfma_f32_32x32x16_bf16(aF1, bF1, c11, 0, 0, 0);

            float sum;
            if (diag) {
                sum = epi_rt<true >(c00, c01, sxx, sgx, rb0, yy0, gy0, yy1, gy1, cj0, cj1)
                    + epi_rt<true >(c10, c11, sxx, sgx, rb1, yy0, gy0, yy1, gy1, cj0, cj1);
            } else {
                sum = epi_rt<false>(c00, c01, sxx, sgx, rb0, yy0, gy0, yy1, gy1, cj0, cj1)
                    + epi_rt<false>(c10, c11, sxx, sgx, rb1, yy0, gy0, yy1, gy1, cj0, cj1);
            }
            if (pp) s_ppn += sum; else s_apn += sum;
            __syncthreads();
        }
    }

    float v4[4] = {s_ppl, s_ppn, s_apl, s_apn};
#pragma unroll
    for (int c = 0; c < 4; ++c) {
        float r = v4[c];
#pragma unroll
        for (int o = 32; o > 0; o >>= 1) r += __shfl_down(r, o, 64);
        if (l == 0) red4[w][c] = r;
    }
    __syncthreads();
    if (t < 4)
        partials[(size_t)blockIdx.x * 4 + t] =
            red4[0][t] + red4[1][t] + red4[2][t] + red4[3][t];
}

extern "C" void kernel_launch(void* const* d_in, const int* in_sizes, int n_in,
                              void* d_out, int out_size, void* d_ws, size_t ws_size,
                              hipStream_t stream)
{
    const float* p       = (const float*)d_in[0];
    const float* p_star  = (const float*)d_in[1];
    const float* a       = (const float*)d_in[2];
    const float* beta    = (const float*)d_in[3];
    const float* gamma   = (const float*)d_in[4];
    const int* edges_pp  = (const int*)d_in[5];
    const int* edges_ap  = (const int*)d_in[6];
    const int* psn       = (const int*)d_in[7];
    const int* pn        = (const int*)d_in[8];
    const int* an        = (const int*)d_in[9];

    char* ws = (char*)d_ws;
    size_t off = 0;
    float* partials = (float*)(ws + off); off += (size_t)GRID_FB * 4 * sizeof(float);
    int2* ps4 = (int2*)(ws + off); off += (size_t)100000 * 8;
    int2* p4  = (int2*)(ws + off); off += (size_t)100000 * 8;
    int2* a4  = (int2*)(ws + off); off += (size_t)50000 * 8;
    u16* gamma_h = (u16*)(ws + off); off += (size_t)(2 * N_PP) * 2;
    u16* beta_h  = (u16*)(ws + off); off += (size_t)N_AP * 2;
    u16* Xb  = (u16*)(ws + off); off += (size_t)BSZ * 32;
    u16* Yp  = (u16*)(ws + off); off += (size_t)BSZ * 32;
    u16* Ya  = (u16*)(ws + off); off += (size_t)BSZ * 32;
    float* Xxx = (float*)(ws + off); off += BSZ * 4;
    float* Xg  = (float*)(ws + off); off += BSZ * 4;
    float* Pyy = (float*)(ws + off); off += BSZ * 4;
    float* Pg  = (float*)(ws + off); off += BSZ * 4;
    float* Ayy = (float*)(ws + off); off += BSZ * 4;
    float* Ag  = (float*)(ws + off); off += BSZ * 4;
    const bool packed = (ws_size >= off);

    if (packed) {
        prep_kernel<<<512, 256, 0, stream>>>(
            p, p_star, a, beta, gamma, psn, pn, an,
            ps4, p4, a4, gamma_h, beta_h,
            Xb, Yp, Ya, Xxx, Xg, Pyy, Pg, Ayy, Ag);
        work_kernel<<<GRID_W, 256, 0, stream>>>(
            edges_pp, edges_ap, ps4, p4, a4, gamma_h, beta_h,
            Xb, Yp, Ya, Xxx, Xg, Pyy, Pg, Ayy, Ag, partials);
        finalize_n<<<1, 256, 0, stream>>>(partials, GRID_W, (float*)d_out);
    } else {
        fused_fb<<<GRID_FB, 256, 0, stream>>>(
            p, p_star, a, beta, gamma, edges_pp, edges_ap, psn, pn, an, partials);
        finalize_n<<<1, 256, 0, stream>>>(partials, GRID_FB, (float*)d_out);
    }
}

// Round 15
// 70.361 us; speedup vs baseline: 1.0984x; 1.0984x over previous
//
#include <hip/hip_runtime.h>

#define N_PP 100000
#define N_A  50000
#define N_AP 150000
#define NEDGE 500000
#define BSZ 8192
#define TILE 128
#define SCALE 1.44269504088896f   // log2(e)
#define QSI4 (1.0f / 7.0f)

#define EB 977                    // edge jobs: 977*512 >= 500000
#define GRID_W 2048               // 8 blocks/CU at VGPR<=64 (8 waves/SIMD cap)
#define EOFF 32                   // edge jobs on blocks [EOFF, EOFF+EB)
#define PP_JOBS 2080              // 64*65/2 upper-tri block pairs
#define AP_JOBS 4096
#define PJOBS (PP_JOBS + AP_JOBS) // 6176 = 3*2048 + 32

#define GRID_FB 2048              // fallback fused grid

typedef __attribute__((ext_vector_type(8)))  short bf16x8;
typedef __attribute__((ext_vector_type(16))) float f32x16;
typedef __attribute__((ext_vector_type(4)))  float f32x4;
typedef unsigned short u16;

#if __has_builtin(__builtin_amdgcn_sqrtf)
#define FAST_SQRT(x) __builtin_amdgcn_sqrtf(x)
#else
#define FAST_SQRT(x) sqrtf(x)
#endif
#if __has_builtin(__builtin_amdgcn_exp2f)
#define FAST_EXP2(x) __builtin_amdgcn_exp2f(x)
#else
#define FAST_EXP2(x) exp2f(x)
#endif

__device__ __forceinline__ u16 f2bf(float f) {
    unsigned u = __builtin_bit_cast(unsigned, f);
    u += 0x7FFFu + ((u >> 16) & 1u);
    return (u16)(u >> 16);
}
__device__ __forceinline__ float bf2f(u16 s) {
    unsigned u = ((unsigned)s) << 16;
    return __builtin_bit_cast(float, u);
}

__device__ __forceinline__ bf16x8 load_frag_f32(const float* __restrict__ src) {
    float4 v0 = *(const float4*)src;
    float4 v1 = *(const float4*)(src + 4);
    bf16x8 f;
    f[0] = (short)f2bf(v0.x); f[1] = (short)f2bf(v0.y);
    f[2] = (short)f2bf(v0.z); f[3] = (short)f2bf(v0.w);
    f[4] = (short)f2bf(v1.x); f[5] = (short)f2bf(v1.y);
    f[6] = (short)f2bf(v1.z); f[7] = (short)f2bf(v1.w);
    return f;
}

// ---- int4 row: 16 coords in 8 bytes (nibble c of word = coord c, signed) ----
__device__ __forceinline__ float dist_i4q(int2 ra, int2 rb) {
    int d2 = 0;
#pragma unroll
    for (int c = 0; c < 8; ++c) {
        int va = (ra.x << (28 - 4 * c)) >> 28;
        int vb = (rb.x << (28 - 4 * c)) >> 28;
        int d = va - vb; d2 += d * d;
        int wa = (ra.y << (28 - 4 * c)) >> 28;
        int wb = (rb.y << (28 - 4 * c)) >> 28;
        int e = wa - wb; d2 += e * e;
    }
    return FAST_SQRT((float)d2) * QSI4;
}

__device__ __forceinline__ unsigned packq4x8(const float* __restrict__ v) {
    unsigned r = 0;
#pragma unroll
    for (int c = 0; c < 8; ++c) {
        int q = (int)rintf(v[c] * 7.0f);
        r |= ((unsigned)(q & 0xF)) << (4 * c);
    }
    return r;
}

__device__ __forceinline__ float pdist16_f32(const float* __restrict__ xv,
                                             const float* __restrict__ yv) {
    float d2 = 1e-12f;
#pragma unroll
    for (int c = 0; c < 16; c += 4) {
        float4 xq = *(const float4*)(xv + c);
        float4 yq = *(const float4*)(yv + c);
        float dx = xq.x - yq.x; d2 = fmaf(dx, dx, d2);
        float dy = xq.y - yq.y; d2 = fmaf(dy, dy, d2);
        float dz = xq.z - yq.z; d2 = fmaf(dz, dz, d2);
        float dw = xq.w - yq.w; d2 = fmaf(dw, dw, d2);
    }
    return sqrtf(d2);
}

// ---------------- prep: int4 tables + bf16 weights + packed bf16 batch ----------------
__global__ __launch_bounds__(256) void prep_kernel(
        const float* __restrict__ p, const float* __restrict__ p_star,
        const float* __restrict__ a, const float* __restrict__ beta,
        const float* __restrict__ gamma,
        const int* __restrict__ psn, const int* __restrict__ pn,
        const int* __restrict__ an,
        int2* __restrict__ ps4, int2* __restrict__ p4, int2* __restrict__ a4,
        u16* __restrict__ gamma_h, u16* __restrict__ beta_h,
        u16* __restrict__ Xb, u16* __restrict__ Yp, u16* __restrict__ Ya,
        float* __restrict__ Xxx, float* __restrict__ Xg,
        float* __restrict__ Pyy, float* __restrict__ Pg,
        float* __restrict__ Ayy, float* __restrict__ Ag)
{
    const int NROWS = 250000;
    const int NBATCH = 3 * BSZ;
    const int NW = 2 * N_PP + N_AP;            // 350000 weight elements
    const int NITEMS = NROWS + NBATCH + NW;
    for (int i = blockIdx.x * 256 + threadIdx.x; i < NITEMS; i += gridDim.x * 256) {
        if (i < NROWS) {
            const float* src; int2* dst;
            if (i < 100000)      { src = p_star + (size_t)i * 16;       dst = ps4 + i; }
            else if (i < 200000) { src = p + (size_t)(i - 100000) * 16; dst = p4 + (i - 100000); }
            else                 { src = a + (size_t)(i - 200000) * 16; dst = a4 + (i - 200000); }
            float buf[16];
            *(float4*)(buf + 0)  = *(const float4*)(src + 0);
            *(float4*)(buf + 4)  = *(const float4*)(src + 4);
            *(float4*)(buf + 8)  = *(const float4*)(src + 8);
            *(float4*)(buf + 12) = *(const float4*)(src + 12);
            int2 q;
            q.x = (int)packq4x8(buf);
            q.y = (int)packq4x8(buf + 8);
            *dst = q;
        } else if (i < NROWS + NBATCH) {
            const int j = i - NROWS;
            const int which = j >> 13;
            const int r = j & (BSZ - 1);
            const float* src; float wsc; u16* drow; float* xxp; float* gp;
            if (which == 0) {
                int node = psn[r]; src = p_star + (size_t)node * 16;
                wsc = gamma[node] * SCALE; drow = Xb + (size_t)r * 16; xxp = Xxx; gp = Xg;
            } else if (which == 1) {
                int node = pn[r]; src = p + (size_t)node * 16;
                wsc = gamma[node + N_PP] * SCALE; drow = Yp + (size_t)r * 16; xxp = Pyy; gp = Pg;
            } else {
                int node = an[r]; src = a + (size_t)(node - N_PP) * 16;
                wsc = beta[node] * SCALE; drow = Ya + (size_t)r * 16; xxp = Ayy; gp = Ag;
            }
            bf16x8 lo = load_frag_f32(src);
            bf16x8 hi = load_frag_f32(src + 8);
            *(bf16x8*)drow = lo;
            *(bf16x8*)(drow + 8) = hi;
            float ss = 0.f;
#pragma unroll
            for (int c = 0; c < 8; ++c) {
                float q0 = bf2f((u16)lo[c]); ss = fmaf(q0, q0, ss);
                float q1 = bf2f((u16)hi[c]); ss = fmaf(q1, q1, ss);
            }
            xxp[r] = ss;
            gp[r] = wsc;
        } else {
            const int j = i - NROWS - NBATCH;
            if (j < 2 * N_PP) gamma_h[j] = f2bf(gamma[j]);
            else              beta_h[j - 2 * N_PP] = f2bf(beta[j - 2 * N_PP]);
        }
    }
}

// single-accumulator epilogue: one 32x32 quadrant (16 regs), stats loaded per q-group
template <bool DIAG>
__device__ __forceinline__ float epi_one(
        const f32x16& c,
        const float* __restrict__ xx, const float* __restrict__ gx,
        int rb, float yy, float gy, int cj)
{
    float s = 0.f;
#pragma unroll
    for (int q = 0; q < 4; ++q) {
        f32x4 xq = *(const f32x4*)&xx[rb + q * 8];
        f32x4 gq = *(const f32x4*)&gx[rb + q * 8];
#pragma unroll
        for (int j = 0; j < 4; ++j) {
            const int reg = q * 4 + j;
            float sq = fmaf(-2.f, c[reg], xq[j] + yy);
            float d  = FAST_SQRT(fmaxf(sq, 1e-12f));
            float v  = FAST_EXP2(fmaf(-SCALE, d, gq[j] + gy));
            if (DIAG) v = (cj > rb + q * 8 + j) ? v : 0.f;
            s += v;
        }
    }
    return s;
}

// two-acc epilogue for the fallback path (unchanged semantics)
template <bool DIAG>
__device__ __forceinline__ float epi_rt(
        const f32x16& ca, const f32x16& cb,
        const float* __restrict__ xxg, const float* __restrict__ gxg,
        int rb, float yy0, float gy0, float yy1, float gy1,
        int cj0, int cj1)
{
    return epi_one<DIAG>(ca, xxg, gxg, rb, yy0, gy0, cj0)
         + epi_one<DIAG>(cb, xxg, gxg, rb, yy1, gy1, cj1);
}

__device__ __forceinline__ void decode_job(int j, int& bx, int& by, bool& pp) {
    pp = (j < PP_JOBS);
    if (pp) {
        int k = j;
        float disc = sqrtf((float)(129 * 129 - 8 * k));
        by = (int)((129.0f - disc) * 0.5f);
        while (64 * by - (by * (by - 1)) / 2 > k) --by;
        while (64 * (by + 1) - ((by + 1) * by) / 2 <= k) ++by;
        bx = by + (k - (64 * by - (by * (by - 1)) / 2));
    } else {
        int k = j - PP_JOBS;
        bx = k & 63; by = k >> 6;
    }
}

// ---------------- work kernel: R13 structure + tail-balancing permutation --------
// block b: [optional] edge job (b-EOFF) if b in [EOFF, EOFF+EB), then
//          pair jobs j = s, s+GRID_W, ... with s = (b + 1039) & 2047 so the 32
//          four-job streams (s < 32) land on blocks 1009-1040 (no edge work).
__global__ __launch_bounds__(256) void work_kernel(
        const int* __restrict__ edges_pp, const int* __restrict__ edges_ap,
        const int2* __restrict__ ps4, const int2* __restrict__ p4,
        const int2* __restrict__ a4,
        const u16* __restrict__ gamma_h, const u16* __restrict__ beta_h,
        const u16* __restrict__ Xb, const u16* __restrict__ Yp,
        const u16* __restrict__ Ya,
        const float* __restrict__ Xxx, const float* __restrict__ Xg,
        const float* __restrict__ Pyy, const float* __restrict__ Pg,
        const float* __restrict__ Ayy, const float* __restrict__ Ag,
        float* __restrict__ epart, float* __restrict__ ppart)
{
    const int b = blockIdx.x;
    const int t = threadIdx.x;
    const int l = t & 63, w = t >> 6;

    float s_ppl = 0.f, s_apl = 0.f;
    const bool has_edge = (b >= EOFF) && (b < EOFF + EB);

    if (has_edge) {
        const int base = (b - EOFF) * 512;
        const int i0 = base + t;
        const int i1raw = base + 256 + t;
        const bool v1 = (i1raw < NEDGE);
        const int i1 = v1 ? i1raw : 0;

        int e0a = __builtin_nontemporal_load(edges_pp + i0);
        int e1a = __builtin_nontemporal_load(edges_pp + NEDGE + i0);
        int f0a = __builtin_nontemporal_load(edges_ap + i0);
        int f1a = __builtin_nontemporal_load(edges_ap + NEDGE + i0);
        int e0b = __builtin_nontemporal_load(edges_pp + i1);
        int e1b = __builtin_nontemporal_load(edges_pp + NEDGE + i1);
        int f0b = __builtin_nontemporal_load(edges_ap + i1);
        int f1b = __builtin_nontemporal_load(edges_ap + NEDGE + i1);

        int2 rA0 = ps4[e0a];
        int2 rA1 = p4[e1a];
        int2 rB0 = ps4[f0a];
        int2 rB1 = a4[f1a - N_PP];
        int2 rC0 = ps4[e0b];
        int2 rC1 = p4[e1b];
        int2 rD0 = ps4[f0b];
        int2 rD1 = a4[f1b - N_PP];
        float wA = bf2f(gamma_h[e0a]) + bf2f(gamma_h[e1a + N_PP]);
        float wB = bf2f(beta_h[f0a])  + bf2f(beta_h[f1a]);
        float wC = bf2f(gamma_h[e0b]) + bf2f(gamma_h[e1b + N_PP]);
        float wD = bf2f(beta_h[f0b])  + bf2f(beta_h[f1b]);

        s_ppl = wA - dist_i4q(rA0, rA1);
        s_apl = wB - dist_i4q(rB0, rB1);
        float tpp2 = wC - dist_i4q(rC0, rC1);
        float tap2 = wD - dist_i4q(rD0, rD1);
        s_ppl += v1 ? tpp2 : 0.f;
        s_apl += v1 ? tap2 : 0.f;
    }

    // ---------------- pair jobs: sequential quadrants, minimal registers ----------
    const int wr = w >> 1, wc = w & 1;
    const int l31 = l & 31, h = l >> 5;
    const int cj0 = wc * 64 + l31, cj1 = cj0 + 32;
    const int rb0 = wr * 64 + 4 * h, rb1 = rb0 + 32;

    float s_ppn = 0.f, s_apn = 0.f;
    const int s = (b + 1039) & 2047;   // tail-balancing permutation

    for (int j = s; j < PJOBS; j += GRID_W) {
        int bx, by; bool pp;
        decode_job(j, bx, by, pp);
        const bool diag = pp && (bx == by);

        const u16* Ytab = pp ? Yp : Ya;
        const int ar0 = by * TILE + wr * 64 + l31;
        const int bc0 = bx * TILE + wc * 64 + l31;
        bf16x8 aF0 = *(const bf16x8*)(Xb   + (size_t)ar0 * 16 + h * 8);
        bf16x8 aF1 = *(const bf16x8*)(Xb   + (size_t)(ar0 + 32) * 16 + h * 8);
        bf16x8 bF0 = *(const bf16x8*)(Ytab + (size_t)bc0 * 16 + h * 8);
        bf16x8 bF1 = *(const bf16x8*)(Ytab + (size_t)(bc0 + 32) * 16 + h * 8);

        const float* yyP = (pp ? Pyy : Ayy) + bx * TILE;
        const float* gyP = (pp ? Pg  : Ag ) + bx * TILE;
        const float* xxg = Xxx + by * TILE;
        const float* gxg = Xg  + by * TILE;
        const float yy0 = yyP[cj0], gy0 = gyP[cj0];
        const float yy1 = yyP[cj1], gy1 = gyP[cj1];

        float sum = 0.f;
        {   // Q00: rows rb0, cols cj0
            f32x16 c;
#pragma unroll
            for (int i = 0; i < 16; ++i) c[i] = 0.f;
            c = __builtin_amdgcn_mfma_f32_32x32x16_bf16(aF0, bF0, c, 0, 0, 0);
            sum += diag ? epi_one<true >(c, xxg, gxg, rb0, yy0, gy0, cj0)
                        : epi_one<false>(c, xxg, gxg, rb0, yy0, gy0, cj0);
        }
        {   // Q01: rows rb0, cols cj1
            f32x16 c;
#pragma unroll
            for (int i = 0; i < 16; ++i) c[i] = 0.f;
            c = __builtin_amdgcn_mfma_f32_32x32x16_bf16(aF0, bF1, c, 0, 0, 0);
            sum += diag ? epi_one<true >(c, xxg, gxg, rb0, yy1, gy1, cj1)
                        : epi_one<false>(c, xxg, gxg, rb0, yy1, gy1, cj1);
        }
        {   // Q10: rows rb1, cols cj0
            f32x16 c;
#pragma unroll
            for (int i = 0; i < 16; ++i) c[i] = 0.f;
            c = __builtin_amdgcn_mfma_f32_32x32x16_bf16(aF1, bF0, c, 0, 0, 0);
            sum += diag ? epi_one<true >(c, xxg, gxg, rb1, yy0, gy0, cj0)
                        : epi_one<false>(c, xxg, gxg, rb1, yy0, gy0, cj0);
        }
        {   // Q11: rows rb1, cols cj1
            f32x16 c;
#pragma unroll
            for (int i = 0; i < 16; ++i) c[i] = 0.f;
            c = __builtin_amdgcn_mfma_f32_32x32x16_bf16(aF1, bF1, c, 0, 0, 0);
            sum += diag ? epi_one<true >(c, xxg, gxg, rb1, yy1, gy1, cj1)
                        : epi_one<false>(c, xxg, gxg, rb1, yy1, gy1, cj1);
        }
        if (pp) s_ppn += sum; else s_apn += sum;
    }

    // ---- one block reduction: 4 categories ----
    __shared__ float red4[4][4];
    float v4[4] = {s_ppl, s_ppn, s_apl, s_apn};
#pragma unroll
    for (int c = 0; c < 4; ++c) {
        float r = v4[c];
#pragma unroll
        for (int o = 32; o > 0; o >>= 1) r += __shfl_down(r, o, 64);
        if (l == 0) red4[w][c] = r;
    }
    __syncthreads();
    if (t < 2) {
        if (has_edge)
            epart[(size_t)(b - EOFF) * 2 + t] =
                red4[0][2 * t] + red4[1][2 * t] + red4[2][2 * t] + red4[3][2 * t];
        ppart[(size_t)b * 2 + t] =
            red4[0][2 * t + 1] + red4[1][2 * t + 1] + red4[2][2 * t + 1] + red4[3][2 * t + 1];
    }
}

// ---------------- finalize (split path) ----------------
__global__ __launch_bounds__(256) void finalize_split(
        const float* __restrict__ epart, const float* __restrict__ ppart,
        float* __restrict__ out)
{
    __shared__ double acc4[4];
    const int t = threadIdx.x;
    const int c = t >> 6, l = t & 63;
    double s = 0.0;
    if (c == 0)      { for (int i = l; i < EB; i += 64)     s += (double)epart[(size_t)i * 2 + 0]; }
    else if (c == 1) { for (int i = l; i < GRID_W; i += 64) s += (double)ppart[(size_t)i * 2 + 0]; }
    else if (c == 2) { for (int i = l; i < EB; i += 64)     s += (double)epart[(size_t)i * 2 + 1]; }
    else             { for (int i = l; i < GRID_W; i += 64) s += (double)ppart[(size_t)i * 2 + 1]; }
#pragma unroll
    for (int o = 32; o > 0; o >>= 1) s += __shfl_down(s, o, 64);
    if (l == 0) acc4[c] = s;
    __syncthreads();
    if (t == 0) {
        double nll_pp = -(acc4[0] - acc4[1]);
        double nll_ap = -(acc4[2] - acc4[3]);
        out[0] = (float)(0.5 * nll_pp / (double)BSZ + 0.5 * nll_ap / (double)BSZ);
    }
}

// ---------------- fallback fused kernel (no workspace tables) ----------------
__global__ __launch_bounds__(256) void fused_fb(
        const float* __restrict__ p, const float* __restrict__ p_star,
        const float* __restrict__ a, const float* __restrict__ beta,
        const float* __restrict__ gamma,
        const int* __restrict__ edges_pp, const int* __restrict__ edges_ap,
        const int* __restrict__ psn, const int* __restrict__ pn,
        const int* __restrict__ an, float* __restrict__ partials)
{
    const int t = threadIdx.x;
    const int l = t & 63, w = t >> 6;
    const int wr = w >> 1, wc = w & 1;
    const int l31 = l & 31, h = l >> 5;

    __shared__ float sxx[TILE], sgx[TILE], syy[TILE], sgy[TILE];
    __shared__ float red4[4][4];

    float s_ppl = 0.f, s_ppn = 0.f, s_apl = 0.f, s_apn = 0.f;
    const int EB_FB = 977;
    const int NJ = EB_FB + PP_JOBS + AP_JOBS;

    for (int j = blockIdx.x; j < NJ; j += gridDim.x) {
        if (j < EB_FB) {
            const int base = j * 512;
#pragma unroll
            for (int k = 0; k < 2; ++k) {
                int i = base + k * 256 + t;
                if (i < NEDGE) {
                    int e0 = edges_pp[i], e1 = edges_pp[NEDGE + i];
                    int f0 = edges_ap[i], f1 = edges_ap[NEDGE + i];
                    s_ppl += gamma[e0] + gamma[e1 + N_PP]
                           - pdist16_f32(p_star + (size_t)e0 * 16, p + (size_t)e1 * 16);
                    s_apl += beta[f0] + beta[f1]
                           - pdist16_f32(p_star + (size_t)f0 * 16, a + (size_t)(f1 - N_PP) * 16);
                }
            }
        } else {
            const bool pp = (j < EB_FB + PP_JOBS);
            int bx, by;
            if (pp) {
                int k = j - EB_FB;
                float disc = sqrtf((float)(129 * 129 - 8 * k));
                by = (int)((129.0f - disc) * 0.5f);
                while (64 * by - (by * (by - 1)) / 2 > k) --by;
                while (64 * (by + 1) - ((by + 1) * by) / 2 <= k) ++by;
                bx = by + (k - (64 * by - (by * (by - 1)) / 2));
            } else {
                int k = j - EB_FB - PP_JOBS;
                bx = k & 63; by = k >> 6;
            }
            const bool diag = pp && (bx == by);
            const float* Y  = pp ? p : a;
            const float* wv = pp ? gamma : beta;
            const int* yn   = pp ? pn : an;
            const int wyo   = pp ? N_PP : 0;
            const int yvo   = pp ? 0 : -N_PP;
            const int ar0 = by * TILE + wr * 64 + l31;
            const int an0 = psn[ar0], an1 = psn[ar0 + 32];
            bf16x8 aF0 = load_frag_f32(p_star + (size_t)an0 * 16 + h * 8);
            bf16x8 aF1 = load_frag_f32(p_star + (size_t)an1 * 16 + h * 8);
            const int bc0g = bx * TILE + wc * 64 + l31;
            const int bn0 = yn[bc0g], bn1 = yn[bc0g + 32];
            bf16x8 bF0 = load_frag_f32(Y + (size_t)(bn0 + yvo) * 16 + h * 8);
            bf16x8 bF1 = load_frag_f32(Y + (size_t)(bn1 + yvo) * 16 + h * 8);
            {
                const bool isx = (t < 128);
                const int  r   = isx ? t : t - 128;
                const int  node = isx ? psn[by * TILE + r] : yn[bx * TILE + r];
                const float* src = isx ? (p_star + (size_t)node * 16)
                                       : (Y + (size_t)(node + yvo) * 16);
                float ss = 0.f;
#pragma unroll
                for (int c = 0; c < 16; c += 4) {
                    float4 v = *(const float4*)(src + c);
                    float q0 = bf2f(f2bf(v.x)), q1 = bf2f(f2bf(v.y));
                    float q2 = bf2f(f2bf(v.z)), q3 = bf2f(f2bf(v.w));
                    ss = fmaf(q0, q0, ss); ss = fmaf(q1, q1, ss);
                    ss = fmaf(q2, q2, ss); ss = fmaf(q3, q3, ss);
                }
                if (isx) { sxx[r] = ss; sgx[r] = wv[node] * SCALE; }
                else     { syy[r] = ss; sgy[r] = wv[node + wyo] * SCALE; }
            }
            __syncthreads();
            const int cj0 = wc * 64 + l31, cj1 = cj0 + 32;
            const float yy0 = syy[cj0], gy0 = sgy[cj0];
            const float yy1 = syy[cj1], gy1 = sgy[cj1];
            const int rb0 = wr * 64 + 4 * h, rb1 = rb0 + 32;

            f32x16 c00, c01, c10, c11;
#pragma unroll
            for (int i = 0; i < 16; ++i) { c00[i] = 0.f; c01[i] = 0.f; c10[i] = 0.f; c11[i] = 0.f; }
            c00 = __builtin_amdgcn_mfma_f32_32x32x16_bf16(aF0, bF0, c00, 0, 0, 0);
            c01 = __builtin_amdgcn_mfma_f32_32x32x16_bf16(aF0, bF1, c01, 0, 0, 0);
            c10 = __builtin_amdgcn_mfma_f32_32x32x16_bf16(aF1, bF0, c10, 0, 0, 0);
            c11 = __builtin_amdgcn_mfma_f32_32x32x16_bf16(aF1, bF1, c11, 0, 0, 0);

            float sum;
            if (diag) {
                sum = epi_rt<true >(c00, c01, sxx, sgx, rb0, yy0, gy0, yy1, gy1, cj0, cj1)
                    + epi_rt<true >(c10, c11, sxx, sgx, rb1, yy0, gy0, yy1, gy1, cj0, cj1);
            } else {
                sum = epi_rt<false>(c00, c01, sxx, sgx, rb0, yy0, gy0, yy1, gy1, cj0, cj1)
                    + epi_rt<false>(c10, c11, sxx, sgx, rb1, yy0, gy0, yy1, gy1, cj0, cj1);
            }
            if (pp) s_ppn += sum; else s_apn += sum;
            __syncthreads();
        }
    }

    float v4[4] = {s_ppl, s_ppn, s_apl, s_apn};
#pragma unroll
    for (int c = 0; c < 4; ++c) {
        float r = v4[c];
#pragma unroll
        for (int o = 32; o > 0; o >>= 1) r += __shfl_down(r, o, 64);
        if (l == 0) red4[w][c] = r;
    }
    __syncthreads();
    if (t < 4)
        partials[(size_t)blockIdx.x * 4 + t] =
            red4[0][t] + red4[1][t] + red4[2][t] + red4[3][t];
}

__global__ __launch_bounds__(256) void finalize_fb(
        const float* __restrict__ partials, float* __restrict__ out)
{
    __shared__ double acc4[4];
    const int t = threadIdx.x;
    const int c = t >> 6, l = t & 63;
    double s = 0.0;
    for (int i = l; i < GRID_FB; i += 64) s += (double)partials[(size_t)i * 4 + c];
#pragma unroll
    for (int o = 32; o > 0; o >>= 1) s += __shfl_down(s, o, 64);
    if (l == 0) acc4[c] = s;
    __syncthreads();
    if (t == 0) {
        double nll_pp = -(acc4[0] - acc4[1]);
        double nll_ap = -(acc4[2] - acc4[3]);
        out[0] = (float)(0.5 * nll_pp / (double)BSZ + 0.5 * nll_ap / (double)BSZ);
    }
}

extern "C" void kernel_launch(void* const* d_in, const int* in_sizes, int n_in,
                              void* d_out, int out_size, void* d_ws, size_t ws_size,
                              hipStream_t stream)
{
    const float* p       = (const float*)d_in[0];
    const float* p_star  = (const float*)d_in[1];
    const float* a       = (const float*)d_in[2];
    const float* beta    = (const float*)d_in[3];
    const float* gamma   = (const float*)d_in[4];
    const int* edges_pp  = (const int*)d_in[5];
    const int* edges_ap  = (const int*)d_in[6];
    const int* psn       = (const int*)d_in[7];
    const int* pn        = (const int*)d_in[8];
    const int* an        = (const int*)d_in[9];

    char* ws = (char*)d_ws;
    size_t off = 0;
    float* ppart = (float*)(ws + off); off += (size_t)GRID_W * 2 * sizeof(float);
    float* epart = (float*)(ws + off); off += (size_t)EB * 2 * sizeof(float);
    int2* ps4 = (int2*)(ws + off); off += (size_t)100000 * 8;
    int2* p4  = (int2*)(ws + off); off += (size_t)100000 * 8;
    int2* a4  = (int2*)(ws + off); off += (size_t)50000 * 8;
    u16* gamma_h = (u16*)(ws + off); off += (size_t)(2 * N_PP) * 2;
    u16* beta_h  = (u16*)(ws + off); off += (size_t)N_AP * 2;
    u16* Xb  = (u16*)(ws + off); off += (size_t)BSZ * 32;
    u16* Yp  = (u16*)(ws + off); off += (size_t)BSZ * 32;
    u16* Ya  = (u16*)(ws + off); off += (size_t)BSZ * 32;
    float* Xxx = (float*)(ws + off); off += BSZ * 4;
    float* Xg  = (float*)(ws + off); off += BSZ * 4;
    float* Pyy = (float*)(ws + off); off += BSZ * 4;
    float* Pg  = (float*)(ws + off); off += BSZ * 4;
    float* Ayy = (float*)(ws + off); off += BSZ * 4;
    float* Ag  = (float*)(ws + off); off += BSZ * 4;
    const bool packed = (ws_size >= off);

    if (packed) {
        prep_kernel<<<512, 256, 0, stream>>>(
            p, p_star, a, beta, gamma, psn, pn, an,
            ps4, p4, a4, gamma_h, beta_h,
            Xb, Yp, Ya, Xxx, Xg, Pyy, Pg, Ayy, Ag);
        work_kernel<<<GRID_W, 256, 0, stream>>>(
            edges_pp, edges_ap, ps4, p4, a4, gamma_h, beta_h,
            Xb, Yp, Ya, Xxx, Xg, Pyy, Pg, Ayy, Ag, epart, ppart);
        finalize_split<<<1, 256, 0, stream>>>(epart, ppart, (float*)d_out);
    } else {
        float* fbpart = (float*)ws;
        fused_fb<<<GRID_FB, 256, 0, stream>>>(
            p, p_star, a, beta, gamma, edges_pp, edges_ap, psn, pn, an, fbpart);
        finalize_fb<<<1, 256, 0, stream>>>(fbpart, (float*)d_out);
    }
}